// Round 1
// baseline (7161.402 us; speedup 1.0000x reference)
//
#include <hip/hip_runtime.h>

// HighwayLayerDiscrete: 256-step recurrent highway net, batch 64, units 1024.
// Phase P = t*4+p: p0: h=lrelu(y@w_y + xproj[t]); p1/p2: h=lrelu(h@w_h[l]+b_h[l]);
// p3: y += h@w_out + b_out; out[:,t,:]=y.
//
// R8 = R7 (6.44 ms) with the lockstep phase pipeline softened to per-wave:
//  1. PER-PRODUCER FLAGS: flags[(rg*32+cg)*4] = phases-done, plain relaxed
//     agent store (R7's single fetch_add serialized 32 RMWs on one LLC line).
//  2. PER-WAVE POLL: lane polls the flag of its OWN K-slice producer
//     (slice s consumes A cols [32s,32s+32) = output of WG (rg, cg=s));
//     wave exits on __all. Ready waves run ahead; poll/stage latency of one
//     wave hides under another's compute (R7 stalled all 8 waves together).
//  3. WAVE-PRIVATE A CHUNKS: a_s[s][8r][32k], pitch 292 (=row 36*8 + 4 skew).
//     Staged and read by the same 16 lanes -> NO stage barrier, no inter-phase
//     a_s barrier (in-wave lgkmcnt ordering). Bank math: quad index mod 8 =
//     (s + r + kq) mod 8 -> b128 writes 8 lanes/quad (min), b128 reads
//     (a + 4*ri + i + q) mod 8 -> all 8 quads once (conflict-free).
//  4. red2 DE-ALIASED from a_s (69.5 KB total LDS) -> compute->red barrier
//     dropped. Barriers/phase: 5 -> 2 (post-red2, post-drain).
// Carried invariants: 256 coop blocks x 512 thr (R4: >256 blocks silently
// fails); no cross-WG split-K (R2/R3); no fences ever (R1: wbl2/inv = 66 ms);
// cross-WG data via relaxed agent-scope atomics (sc1 at LLC); release =
// waitcnt0+barrier+flag store; acquire = per-wave poll + asm clobber;
// W register prefetch one phase ahead (R7).

constexpr int B = 64, T = 256, U = 1024, E = 512;
constexpr int BU = B * U;    // 65536
constexpr int CPITCH = 292;  // per-s A-chunk pitch: 8 rows * 36 + 4 skew
constexpr int RPITCH = 264;  // red2 per-s pitch (R7-proven spread)

#define LRELU(v) ((v) > 0.f ? (v) : 0.2f * (v))

using f4 = float __attribute__((ext_vector_type(4)));

__device__ __forceinline__ unsigned long long llc_load64(const float* p) {
  return __hip_atomic_load((const unsigned long long*)p, __ATOMIC_RELAXED,
                           __HIP_MEMORY_SCOPE_AGENT);
}
__device__ __forceinline__ void llc_store(float* p, float v) {
  __hip_atomic_store(p, v, __ATOMIC_RELAXED, __HIP_MEMORY_SCOPE_AGENT);
}
__device__ __forceinline__ unsigned llc_flag(const unsigned* p) {
  return __hip_atomic_load(p, __ATOMIC_RELAXED, __HIP_MEMORY_SCOPE_AGENT);
}
__device__ __forceinline__ void llc_flag_store(unsigned* p, unsigned v) {
  __hip_atomic_store(p, v, __ATOMIC_RELAXED, __HIP_MEMORY_SCOPE_AGENT);
}

// ---------------- init: zero flags, y0 into slot1 and ybuf ----------------
__global__ void k_init(float* __restrict__ slot1, float* __restrict__ ybuf,
                       const float* __restrict__ h0,
                       unsigned* __restrict__ flags) {
  int tid = blockIdx.x * 256 + threadIdx.x;
  if (tid < 1024) flags[tid] = 0u;  // 256 flag slots, stride 4 uints
  if (tid < BU) {
    float v = h0[tid & (U - 1)];
    slot1[tid] = v;
    ybuf[tid] = v;
  }
}

// ------- xproj[t*64+n][u] = emb[x[n][t]] @ w_x + b_in (R2/R3-proven) -------
__global__ __launch_bounds__(256) void k_xproj(
    const int* __restrict__ x, const float* __restrict__ emb,
    const float* __restrict__ w_x, const float* __restrict__ b_in,
    float* __restrict__ xp) {
  __shared__ float a_s[64][36];
  __shared__ float w_s[32][64];
  __shared__ int idxs[64];
  const int tid = threadIdx.x;
  const int m0 = blockIdx.x * 64;
  const int c0 = blockIdx.y * 64;
  if (tid < 64) {
    int m = m0 + tid;
    idxs[tid] = x[(m & 63) * T + (m >> 6)];  // x[n][t], row m = t*64+n
  }
  __syncthreads();
  const int rq = tid >> 4, cq = tid & 15;
  float acc[4][4] = {};
  for (int k0 = 0; k0 < E; k0 += 32) {
#pragma unroll
    for (int rep = 0; rep < 8; ++rep) {
      int e = rep * 256 + tid;
      int r = e >> 5, k = e & 31;
      a_s[r][k] = emb[(size_t)idxs[r] * E + k0 + k];
    }
#pragma unroll
    for (int rep = 0; rep < 2; ++rep) {
      int e = rep * 256 + tid;
      int kr = e >> 4, q = e & 15;
      *(float4*)&w_s[kr][4 * q] =
          *(const float4*)(w_x + (size_t)(k0 + kr) * U + c0 + 4 * q);
    }
    __syncthreads();
#pragma unroll
    for (int kc = 0; kc < 32; kc += 4) {
      float4 a4[4], w4[4];
#pragma unroll
      for (int i = 0; i < 4; ++i) a4[i] = *(const float4*)&a_s[4 * rq + i][kc];
#pragma unroll
      for (int kk = 0; kk < 4; ++kk)
        w4[kk] = *(const float4*)&w_s[kc + kk][4 * cq];
#pragma unroll
      for (int i = 0; i < 4; ++i) {
        const float av[4] = {a4[i].x, a4[i].y, a4[i].z, a4[i].w};
#pragma unroll
        for (int kk = 0; kk < 4; ++kk) {
          acc[i][0] += av[kk] * w4[kk].x;
          acc[i][1] += av[kk] * w4[kk].y;
          acc[i][2] += av[kk] * w4[kk].z;
          acc[i][3] += av[kk] * w4[kk].w;
        }
      }
    }
    __syncthreads();
  }
  const float4 bb = *(const float4*)(b_in + c0 + 4 * cq);
  const float bv[4] = {bb.x, bb.y, bb.z, bb.w};
#pragma unroll
  for (int i = 0; i < 4; ++i) {
    float4 o;
    o.x = acc[i][0] + bv[0];
    o.y = acc[i][1] + bv[1];
    o.z = acc[i][2] + bv[2];
    o.w = acc[i][3] + bv[3];
    *(float4*)(xp + (size_t)(m0 + 4 * rq + i) * U + c0 + 4 * cq) = o;
  }
}

// ---------------- sequential pipeline ----------------
// 256 WGs = 8 rg x 32 cg (XCD = cg&7, L2-affine). Thread (s,ri,ci): K-slice
// [32s,32s+32), rows [4ri,4ri+4) of 8, cols [4ci,4ci+4) of 32. A chunk for
// slice s is wave-private: staged + read by the same 16 lanes. Partials ->
// red2[s][out] pitch 264 (separate buffer), reduced by tid<256 after B1.
__global__ __launch_bounds__(512, 2) void k_seq(
    const float* __restrict__ xp, const float* __restrict__ w_y,
    const float* __restrict__ w_h, const float* __restrict__ b_h,
    const float* __restrict__ w_out, const float* __restrict__ b_out,
    float* __restrict__ out, float* __restrict__ slots,
    float* __restrict__ ybuf, unsigned* __restrict__ flags) {
  __shared__ float a_s[32 * CPITCH];   // 9344 floats = 37376 B
  __shared__ float red2[32 * RPITCH];  // 8448 floats = 33792 B
  const int tid = threadIdx.x;
  const int cg = blockIdx.x & 31, rg = blockIdx.x >> 5;
  const int l = tid & 63;
  const int ci = l & 7, ri = (l >> 3) & 1, lane16 = l & 15;
  const int s = (tid >> 6) * 4 + ((l >> 4) & 3);
  const int cb = 4 * ci, r0 = 4 * ri, k0 = 32 * s;
  unsigned* const myflag = &flags[(rg * 32 + cg) * 4];
  const unsigned* const pollflag = &flags[(rg * 32 + s) * 4];

  // W base selector for phase P
  auto wbase = [&](int P) -> const float* {
    const int p = P & 3;
    const float* Wsrc = (p == 0)   ? w_y
                        : (p == 3) ? w_out
                                   : w_h + (size_t)(p - 1) * U * U;
    return Wsrc + (size_t)k0 * U + 32 * cg + cb;
  };
  // ---- W prefetch for P=0 (static addresses -> latency off critical path) --
  f4 wreg[32];  // W[k0+j][cb..cb+4), j=0..31
  {
    const float* wp = wbase(0);
#pragma unroll
    for (int j = 0; j < 32; ++j) wreg[j] = *(const f4*)(wp + (size_t)j * U);
  }

  for (int P = 0; P < 4 * T; ++P) {
    const int t = P >> 2, p = P & 3;
    const float* Asrc =
        slots + (size_t)((P + 1) & 1) * BU + (size_t)(8 * rg) * U;
    float* slotw = slots + (size_t)(P & 1) * BU;
    // ---- 1. per-wave poll: each lane waits on its K-slice producer ----
    if (P > 0) {
      const unsigned tg = (unsigned)P;
      unsigned f = llc_flag(pollflag);
      while (!__all((int)(f >= tg))) {
        __builtin_amdgcn_s_sleep(1);
        f = llc_flag(pollflag);
      }
      asm volatile("" ::: "memory");
    }
    // ---- 2. stage A chunk [8 rows][32 k] by its own 16-lane group ----
    //      (no barrier: same lanes read it; in-wave lgkmcnt orders wr->rd)
#pragma unroll
    for (int rep = 0; rep < 4; ++rep) {
      const int j = rep * 16 + lane16;  // f4 index within chunk [0,64)
      const int r = j >> 3, kq = j & 7;
      const float* pa = Asrc + (size_t)r * U + k0 + 4 * kq;
      unsigned long long v0 = llc_load64(pa);
      unsigned long long v1 = llc_load64(pa + 2);
      f4 v;
      ((unsigned long long*)&v)[0] = v0;
      ((unsigned long long*)&v)[1] = v1;
      *(f4*)&a_s[s * CPITCH + r * 36 + 4 * kq] = v;
    }
    // ---- 3. main: 4x4x(K=32) tile; A from LDS, W from registers ----
    f4 acc[4];
#pragma unroll
    for (int i = 0; i < 4; ++i) acc[i] = (f4){0.f, 0.f, 0.f, 0.f};
    {
      const int abase = s * CPITCH + r0 * 36;
#pragma unroll
      for (int q = 0; q < 8; ++q) {
        const int ai = abase + 4 * q;
        f4 a0 = *(const f4*)&a_s[ai];
        f4 a1 = *(const f4*)&a_s[ai + 36];
        f4 a2 = *(const f4*)&a_s[ai + 72];
        f4 a3 = *(const f4*)&a_s[ai + 108];
        const f4 w0 = wreg[4 * q], w1 = wreg[4 * q + 1];
        const f4 w2 = wreg[4 * q + 2], w3 = wreg[4 * q + 3];
        acc[0] += a0.x * w0 + a0.y * w1 + a0.z * w2 + a0.w * w3;
        acc[1] += a1.x * w0 + a1.y * w1 + a1.z * w2 + a1.w * w3;
        acc[2] += a2.x * w0 + a2.y * w1 + a2.z * w2 + a2.w * w3;
        acc[3] += a3.x * w0 + a3.y * w1 + a3.z * w2 + a3.w * w3;
      }
    }
    // ---- 4. write partials red2[s*264 + out], b128 (no pre-barrier:
    //         red2 no longer aliases a_s) ----
#pragma unroll
    for (int i = 0; i < 4; ++i)
      *(f4*)&red2[s * RPITCH + (r0 + i) * 32 + cb] = acc[i];
    __syncthreads();  // B1: all partials visible
    // ---- 5. finalize: 256 threads, sum 32 partials, bias+act, store ----
    if (tid < 256) {
      float sum = 0.f;
#pragma unroll
      for (int z = 0; z < 32; ++z) sum += red2[z * RPITCH + tid];
      const int row = 8 * rg + (tid >> 5);
      const int u = 32 * cg + (tid & 31);
      if (p == 0) {
        float v = sum + xp[((size_t)t * B + row) * U + u];
        llc_store(slotw + (size_t)row * U + u, LRELU(v));
      } else if (p < 3) {
        float v = sum + b_h[(p - 1) * U + u];
        llc_store(slotw + (size_t)row * U + u, LRELU(v));
      } else {
        const size_t yi = (size_t)row * U + u;
        float yn = ybuf[yi] + sum + b_out[u];  // WG-private: plain ok
        ybuf[yi] = yn;
        out[((size_t)row * T + t) * U + u] = yn;
        llc_store(slotw + yi, yn);  // y is next p0's A
      }
    }
    // ---- 6. drain: all stores at LLC before the flag post ----
    asm volatile("" ::: "memory");
    __builtin_amdgcn_s_waitcnt(0);
    __syncthreads();  // B2: finalize reads of red2 also done before next phase
    // ---- 7. W prefetch for P+1 (issued BEFORE the flag post so the L2 W
    //         traffic overlaps post + poll + A-stage of the next phase) ----
    if (P < 4 * T - 1) {
      const float* wp = wbase(P + 1);
#pragma unroll
      for (int j = 0; j < 32; ++j) wreg[j] = *(const f4*)(wp + (size_t)j * U);
    }
    if (tid == 0) llc_flag_store(myflag, (unsigned)(P + 1));
  }
}

extern "C" void kernel_launch(void* const* d_in, const int* in_sizes, int n_in,
                              void* d_out, int out_size, void* d_ws,
                              size_t ws_size, hipStream_t stream) {
  const int* x = (const int*)d_in[0];
  const float* emb = (const float*)d_in[1];
  const float* w_y = (const float*)d_in[2];
  const float* w_x = (const float*)d_in[3];
  const float* b_in = (const float*)d_in[4];
  const float* w_h = (const float*)d_in[5];
  const float* b_h = (const float*)d_in[6];
  const float* w_out = (const float*)d_in[7];
  const float* b_out = (const float*)d_in[8];
  const float* h0 = (const float*)d_in[9];
  float* out = (float*)d_out;

  // workspace (floats): xproj | slots[2] | ybuf | flags
  float* ws = (float*)d_ws;
  float* xpb = ws;                         // T*B*U
  float* slots = xpb + (size_t)T * B * U;  // 2*BU
  float* ybuf = slots + 2 * (size_t)BU;    // BU
  unsigned* flags = (unsigned*)(ybuf + (size_t)BU);  // 1024 uints

  k_init<<<256, 256, 0, stream>>>(slots + (size_t)BU, ybuf, h0, flags);
  dim3 g1(256, 16);
  k_xproj<<<g1, 256, 0, stream>>>(x, emb, w_x, b_in, xpb);

  void* args[] = {&xpb,   &w_y, &w_h,   &b_h,  &w_out,
                  &b_out, &out, &slots, &ybuf, &flags};
  hipLaunchCooperativeKernel((void*)k_seq, dim3(256), dim3(512), args, 0u,
                             stream);
}